// Round 15
// baseline (385.318 us; speedup 1.0000x reference)
//
#include <hip/hip_runtime.h>
#include <hip/hip_bf16.h>

#define NN 32768
#define NE 524288
#define HID 128

typedef unsigned short u16;
typedef unsigned int u32;
typedef __bf16 bf16x8 __attribute__((ext_vector_type(8)));
typedef float f32x4 __attribute__((ext_vector_type(4)));

__device__ __forceinline__ u16 f2bf(float f) {
  return __builtin_bit_cast(u16, (__bf16)f);   // RNE via v_cvt
}
__device__ __forceinline__ float bf2f(u16 h) {
  return __builtin_bit_cast(float, (u32)h << 16);
}
__device__ __forceinline__ float silu_f(float v) {
  return v * __builtin_amdgcn_rcpf(1.f + __expf(-v));
}
__device__ __forceinline__ bf16x8 cvt8(float4 a, float4 b) {
  bf16x8 r;
  r[0] = (__bf16)a.x; r[1] = (__bf16)a.y; r[2] = (__bf16)a.z; r[3] = (__bf16)a.w;
  r[4] = (__bf16)b.x; r[5] = (__bf16)b.y; r[6] = (__bf16)b.z; r[7] = (__bf16)b.w;
  return r;
}
__device__ __forceinline__ float4 f4fma(float4 x, float4 s, float inv) {
  return make_float4(x.x + s.x * inv, x.y + s.y * inv,
                     x.z + s.z * inv, x.w + s.w * inv);
}

// async global->LDS, 16B/lane; LDS dest = wave-uniform base + lane*16
__device__ __forceinline__ void gld16(const void* g, void* l) {
  __builtin_amdgcn_global_load_lds(
      (const __attribute__((address_space(1))) u32*)g,
      (__attribute__((address_space(3))) u32*)l, 16, 0, 0);
}

#define WV(N)  do { asm volatile("s_waitcnt vmcnt(" #N ")" ::: "memory"); \
                    __builtin_amdgcn_sched_barrier(0); } while (0)
#define WL()   do { asm volatile("s_waitcnt lgkmcnt(0)" ::: "memory"); \
                    __builtin_amdgcn_sched_barrier(0); } while (0)
__device__ __forceinline__ void bar() {
  __builtin_amdgcn_sched_barrier(0);
  __builtin_amdgcn_s_barrier();
  __builtin_amdgcn_sched_barrier(0);
}

// ---------------------------------------------------------------- prep ----
// VECTORIZED (float4/thread): x->bf16; w1/w2 -> col-major + 16B-chunk XOR
// pre-swizzle (w1Ts||w2Ts contiguous); wu1/wu2 plain col-major; fused
// recv-degree count (cnt pre-zeroed). Grid = NN*HID/4/256 = 4096 blocks;
// i covers [0, 1048576) > NE so the edge count is complete.
__global__ __launch_bounds__(256) void prep_k(
    const float* __restrict__ x, const float* __restrict__ w1,
    const float* __restrict__ w2, const float* __restrict__ wu1,
    const float* __restrict__ wu2, const int* __restrict__ recv,
    u16* __restrict__ xb, u16* __restrict__ w1Ts, u16* __restrict__ w2Ts,
    u16* __restrict__ wu1T, u16* __restrict__ wu2T, int* __restrict__ cnt)
{
  int i = blockIdx.x * 256 + threadIdx.x;     // 1048576 threads
  float4 xv = reinterpret_cast<const float4*>(x)[i];
  uint2 pv;
  pv.x = (u32)f2bf(xv.x) | ((u32)f2bf(xv.y) << 16);
  pv.y = (u32)f2bf(xv.z) | ((u32)f2bf(xv.w) << 16);
  reinterpret_cast<uint2*>(xb)[i] = pv;
  if (i < NE) atomicAdd(&cnt[recv[i]], 1);
  if (i < 3 * 128 * 128) {                    // w1Ts [s][c][q^(c&7)][j]
    int j = i & 7, qs = (i >> 3) & 15, c = (i >> 7) & 127, s = i >> 14;
    int k = s * 128 + ((qs ^ (c & 7)) << 3) + j;
    w1Ts[i] = f2bf(w1[k * 128 + c]);
  }
  if (i < 128 * 128) {                        // w2Ts [c][q^(c&7)][j]
    int j = i & 7, qs = (i >> 3) & 15, c = i >> 7;
    int k = ((qs ^ (c & 7)) << 3) + j;
    w2Ts[i] = f2bf(w2[k * 128 + c]);
  }
  if (i < 256 * 128) { int c = i >> 7, k = i & 127; wu1T[i] = f2bf(wu1[k * 256 + c]); }
  if (i < 128 * 256) { int c = i >> 8, k = i & 255; wu2T[i] = f2bf(wu2[k * 128 + c]); }
}

// exclusive scan of cnt[NN] -> cursor
__global__ __launch_bounds__(1024) void scan_k(const int* __restrict__ cnt,
                                               int* __restrict__ cursor)
{
  __shared__ int part[1024];
  const int tid = threadIdx.x;
  const int base = tid * 32;
  int v[32];
  int s = 0;
  #pragma unroll
  for (int j = 0; j < 32; ++j) { v[j] = cnt[base + j]; s += v[j]; }
  part[tid] = s;
  __syncthreads();
  #pragma unroll 1
  for (int d = 1; d < 1024; d <<= 1) {
    int t = (tid >= d) ? part[tid - d] : 0;
    __syncthreads();
    part[tid] += t;
    __syncthreads();
  }
  int ex = part[tid] - s;
  #pragma unroll
  for (int j = 0; j < 32; ++j) {
    cursor[base + j] = ex;
    ex += v[j];
  }
}

// CSR scatter; also pre-gathers send/recv into CSR order (sid/rid).
__global__ __launch_bounds__(256) void scatter_k(const int* __restrict__ send,
                                                 const int* __restrict__ recv,
                                                 int* __restrict__ cursor,
                                                 int* __restrict__ eperm,
                                                 int* __restrict__ sid,
                                                 int* __restrict__ rid)
{
  int e = blockIdx.x * 256 + threadIdx.x;
  int r = recv[e];
  int s = send[e];
  int pos = atomicAdd(&cursor[r], 1);
  eperm[pos] = e;
  sid[pos] = s;
  rid[pos] = r;
}

// ------------------------------------------------------------ edge MLP ----
// 3-blocks/CU phased kernel: 128 CSR edges/block, 8 waves, LDS 48.5KB
// (sA[128][128] 32KB + HALF B panel sB[64][128] 16KB + sNid). Wave tile
// 32x32 per half; acc[half][2][2]. Block-staged gld16 (register-lean,
// R3 family: VGPR ~60-80) + (512,6) -> 24 waves/CU = 6 waves/SIMD; three
// independent blocks decorrelate barrier stalls. eattr loaded inline at
// slice 2 (R3-proven). Fused segmented scatter-mean epilogue.
// R15 fix vs R14: stageB chunk stride 512 u16 (= 1024 B), not 1024 u16 —
// R14's stride wrote 2x past sB (LDS OOB -> abort).
__global__ __launch_bounds__(512, 6) void edge_mlp(
    const u16* __restrict__ xb, const float* __restrict__ eattr,
    const int* __restrict__ eperm, const int* __restrict__ sid,
    const int* __restrict__ rid,
    const u16* __restrict__ wTs, const float* __restrict__ b1,
    const float* __restrict__ b2,
    float* __restrict__ msg_out, float* __restrict__ sums)
{
  __shared__ u16 sA[128 * 128];   // 32KB: A slices -> hidden -> msg-bf16
  __shared__ u16 sB[64 * 128];    // 16KB: one 64-col B half-panel
  __shared__ int sNid[128];

  const int tid  = threadIdx.x;
  const int lane = tid & 63;
  const int w    = tid >> 6;      // 0..7
  const int wr   = w >> 1;        // 0..3: 32-edge stripe
  const int wc   = w & 1;         // 0..1: col-32 within the current 64-col half
  const int fr   = lane & 15;
  const int fkq  = lane >> 4;
  const int orow = fkq * 4;
  const int lrow4 = lane >> 4;
  const int schk  = lane & 15;
  // bijective XCD-chunked tile mapping (gridDim = 4096, 4096 % 8 == 0)
  const int logical = ((int)blockIdx.x & 7) * ((int)gridDim.x >> 3)
                    + ((int)blockIdx.x >> 3);
  const int e0 = logical * 128;

  // ---- ids for this wave's 16 staging rows (single-hop: sid/rid) ----
  int eo[4], ns[4], nr[4], rl[4];
  #pragma unroll
  for (int i = 0; i < 4; ++i) {
    rl[i] = w * 16 + i * 4 + lrow4;
    eo[i] = eperm[e0 + rl[i]];
    ns[i] = sid[e0 + rl[i]];
    nr[i] = rid[e0 + rl[i]];
  }
  #pragma unroll
  for (int i = 0; i < 4; ++i)
    if (schk == 0) sNid[rl[i]] = nr[i];

  // bias values: col = h*64 + wc*32 + n*16 + fr
  float b1v[2][2], b2v[2][2];
  #pragma unroll
  for (int h = 0; h < 2; ++h)
    #pragma unroll
    for (int n = 0; n < 2; ++n) {
      int c = h * 64 + wc * 32 + n * 16 + fr;
      b1v[h][n] = b1[c];
      b2v[h][n] = b2[c];
    }

  f32x4 acc[2][2][2];             // [half][m][n]
  #pragma unroll
  for (int h = 0; h < 2; ++h)
    #pragma unroll
    for (int m = 0; m < 2; ++m)
      #pragma unroll
      for (int n = 0; n < 2; ++n)
        #pragma unroll
        for (int r = 0; r < 4; ++r) acc[h][m][n][r] = 0.f;

  // ---- staging helpers ----
  auto stageA = [&](const int (&node)[4]) {
    #pragma unroll
    for (int i = 0; i < 4; ++i)
      gld16(xb + ((size_t)node[i] << 7) + ((schk ^ (rl[i] & 7)) << 3),
            sA + ((w * 16 + i * 4) << 7));
  };
  // stage 16KB half-panel: 16 chunks x 512 u16 (1024B each; 64 lanes x 16B)
  auto stageB = [&](int panel, int h) {
    const u16* src = wTs + panel * 16384 + h * 8192;
    gld16(src + (w * 2 + 0) * 512 + lane * 8, sB + (w * 2 + 0) * 512);
    gld16(src + (w * 2 + 1) * 512 + lane * 8, sB + (w * 2 + 1) * 512);
  };

  // one 32x32 half-pass vs current sB
  auto chalf = [&](f32x4 (&a)[2][2]) {
    #pragma unroll
    for (int kk = 0; kk < 4; ++kk) {
      bf16x8 aF[2], bF[2];
      #pragma unroll
      for (int m = 0; m < 2; ++m) {
        int row = wr * 32 + m * 16 + fr;
        int ch = (kk * 4 + fkq) ^ (row & 7);
        aF[m] = __builtin_bit_cast(bf16x8,
            *reinterpret_cast<const uint4*>(sA + (row << 7) + (ch << 3)));
      }
      #pragma unroll
      for (int n = 0; n < 2; ++n) {
        int cl = wc * 32 + n * 16 + fr;
        int ch = (kk * 4 + fkq) ^ (cl & 7);
        bF[n] = __builtin_bit_cast(bf16x8,
            *reinterpret_cast<const uint4*>(sB + (cl << 7) + (ch << 3)));
      }
      __builtin_amdgcn_s_setprio(1);
      #pragma unroll
      for (int m = 0; m < 2; ++m)
        #pragma unroll
        for (int n = 0; n < 2; ++n)
          a[m][n] = __builtin_amdgcn_mfma_f32_16x16x32_bf16(aF[m], bF[n], a[m][n], 0, 0, 0);
      __builtin_amdgcn_s_setprio(0);
    }
  };

  // ---- slice 0: x[send] ----
  stageA(ns);
  stageB(0, 0);                    // W1a half0
  WV(0); bar();
  chalf(acc[0]); bar();            // s0 h0
  stageB(0, 1); WV(0); bar();
  chalf(acc[1]); bar();            // s0 h1

  // ---- slice 1: x[recv] ----
  stageA(nr);
  stageB(1, 0);
  WV(0); bar();
  chalf(acc[0]); bar();            // s1 h0
  stageB(1, 1); WV(0); bar();
  chalf(acc[1]); bar();            // s1 h1

  // ---- slice 2: eattr inline (load f32, cvt, swizzled ds_write) ----
  stageB(2, 0);
  #pragma unroll
  for (int i = 0; i < 4; ++i) {
    const float* ep = eattr + ((size_t)eo[i] << 7) + ((schk ^ (rl[i] & 7)) << 3);
    float4 v0 = *reinterpret_cast<const float4*>(ep);
    float4 v1 = *reinterpret_cast<const float4*>(ep + 4);
    *reinterpret_cast<uint4*>(sA + (rl[i] << 7) + (schk << 3)) =
        __builtin_bit_cast(uint4, cvt8(v0, v1));
  }
  WV(0); WL(); bar();
  chalf(acc[0]); bar();            // s2 h0
  stageB(2, 1); WV(0); bar();
  chalf(acc[1]); bar();            // s2 h1

  // hidden = silu(acc + b1) -> sA (swizzled b16) + stage W2 half0; reset acc
  stageB(3, 0);
  #pragma unroll
  for (int h = 0; h < 2; ++h)
    #pragma unroll
    for (int m = 0; m < 2; ++m)
      #pragma unroll
      for (int n = 0; n < 2; ++n) {
        int c = h * 64 + wc * 32 + n * 16 + fr;
        #pragma unroll
        for (int r = 0; r < 4; ++r) {
          int row = wr * 32 + m * 16 + orow + r;
          sA[(row << 7) + (((c >> 3) ^ (row & 7)) << 3) + (c & 7)] =
              f2bf(silu_f(acc[h][m][n][r] + b1v[h][n]));
          acc[h][m][n][r] = 0.f;
        }
      }
  WV(0); WL(); bar();
  chalf(acc[0]); bar();            // W2 h0
  stageB(3, 1); WV(0); bar();
  chalf(acc[1]);                   // W2 h1

  // epilogue edge ids (C/D rows)
  int eg[2][4];
  #pragma unroll
  for (int m = 0; m < 2; ++m)
    #pragma unroll
    for (int r = 0; r < 4; ++r)
      eg[m][r] = eperm[e0 + wr * 32 + m * 16 + orow + r];
  bar();                           // all slice-3 sA reads done

  // msg = silu(acc + b2) -> global f32 + bf16 -> sA for the reduce
  #pragma unroll
  for (int m = 0; m < 2; ++m)
    #pragma unroll
    for (int r = 0; r < 4; ++r) {
      int row = wr * 32 + m * 16 + orow + r;
      float* mp = msg_out + ((size_t)eg[m][r] << 7);
      #pragma unroll
      for (int h = 0; h < 2; ++h)
        #pragma unroll
        for (int n = 0; n < 2; ++n) {
          int c = h * 64 + wc * 32 + n * 16 + fr;
          float v = silu_f(acc[h][m][n][r] + b2v[h][n]);
          mp[c] = v;
          sA[(row << 7) + (((c >> 3) ^ (row & 7)) << 3) + (c & 7)] = f2bf(v);
        }
    }
  WL(); bar();

  // segmented column reduce: 4 groups x 32 rows, 128 cols
  {
    const int col = tid & 127, q = tid >> 7;
    float s = 0.f;
    int cur = sNid[q * 32];
    #pragma unroll 1
    for (int r = 0; r < 32; ++r) {
      int row = q * 32 + r;
      u16 hv = sA[(row << 7) + (((col >> 3) ^ (row & 7)) << 3) + (col & 7)];
      s += bf2f(hv);
      int nxt = (r < 31) ? sNid[row + 1] : -1;
      if (nxt != cur) {
        atomicAdd(sums + (size_t)cur * HID + col, s);
        s = 0.f;
        cur = nxt;
      }
    }
  }
}

// ----------------------------------------------------------- update MLP ----
// t = silu((x + sums/cnt) @ wu1 + bu1)  [NN,256] — xin fused into A-fragments
__global__ __launch_bounds__(256) void mlp1_k(
    const float* __restrict__ x, const float* __restrict__ sums,
    const int* __restrict__ cnt, const u16* __restrict__ wu1T,
    const float* __restrict__ bu1, u16* __restrict__ t)
{
  __shared__ u16 sB[256][40];
  const int tid = threadIdx.x, lane = tid & 63, wid = tid >> 6;
  const int wr = wid >> 1, wc = wid & 1;
  const int fr = lane & 15, fkq = lane >> 4, fk = fkq * 8, orow = fkq * 4;
  const int n0 = blockIdx.x * 64;

  float invm[2];
  #pragma unroll
  for (int m = 0; m < 2; ++m)
    invm[m] = __builtin_amdgcn_rcpf(fmaxf((float)cnt[n0 + wr * 32 + m * 16 + fr], 1.f));

  f32x4 acc[2][8];
  #pragma unroll
  for (int m = 0; m < 2; ++m)
    #pragma unroll
    for (int n = 0; n < 8; ++n)
      #pragma unroll
      for (int r = 0; r < 4; ++r) acc[m][n][r] = 0.f;

  #pragma unroll 1
  for (int kk = 0; kk < 4; ++kk) {
    #pragma unroll
    for (int it = 0; it < 4; ++it) {
      int chunk = tid + it * 256;
      int c = chunk >> 2, q = chunk & 3;
      *reinterpret_cast<uint4*>(&sB[c][q * 8]) =
          *reinterpret_cast<const uint4*>(wu1T + c * 128 + kk * 32 + q * 8);
    }
    __syncthreads();
    bf16x8 aF[2], bF[8];
    #pragma unroll
    for (int m = 0; m < 2; ++m) {
      size_t basei = (size_t)(n0 + wr * 32 + m * 16 + fr) * HID + kk * 32 + fk;
      float4 xv0 = *reinterpret_cast<const float4*>(x + basei);
      float4 xv1 = *reinterpret_cast<const float4*>(x + basei + 4);
      float4 sv0 = *reinterpret_cast<const float4*>(sums + basei);
      float4 sv1 = *reinterpret_cast<const float4*>(sums + basei + 4);
      aF[m] = cvt8(f4fma(xv0, sv0, invm[m]), f4fma(xv1, sv1, invm[m]));
    }
    #pragma unroll
    for (int n = 0; n < 8; ++n)
      bF[n] = __builtin_bit_cast(bf16x8,
          *reinterpret_cast<const uint4*>(&sB[wc * 128 + n * 16 + fr][fk]));
    #pragma unroll
    for (int m = 0; m < 2; ++m)
      #pragma unroll
      for (int n = 0; n < 8; ++n)
        acc[m][n] = __builtin_amdgcn_mfma_f32_16x16x32_bf16(aF[m], bF[n], acc[m][n], 0, 0, 0);
    __syncthreads();
  }
  #pragma unroll
  for (int n = 0; n < 8; ++n) {
    int col = wc * 128 + n * 16 + fr;
    float bb = bu1[col];
    #pragma unroll
    for (int m = 0; m < 2; ++m) {
      int row = n0 + wr * 32 + m * 16 + orow;
      #pragma unroll
      for (int r = 0; r < 4; ++r)
        t[(size_t)(row + r) * 256 + col] = f2bf(silu_f(acc[m][n][r] + bb));
    }
  }
}

// xo = (x + sums/cnt) + t @ wu2 + bu2   (residual recomputed in f32)
__global__ __launch_bounds__(256) void mlp2_k(
    const u16* __restrict__ t, const u16* __restrict__ wu2T,
    const float* __restrict__ bu2, const float* __restrict__ x,
    const float* __restrict__ sums, const int* __restrict__ cnt,
    float* __restrict__ xo)
{
  __shared__ u16 sB[128][40];
  const int tid = threadIdx.x, lane = tid & 63, wid = tid >> 6;
  const int wr = wid >> 1, wc = wid & 1;
  const int fr = lane & 15, fk = (lane >> 4) * 8, orow = (lane >> 4) * 4;
  const int n0 = blockIdx.x * 64;

  f32x4 acc[2][4];
  #pragma unroll
  for (int m = 0; m < 2; ++m)
    #pragma unroll
    for (int n = 0; n < 4; ++n)
      #pragma unroll
      for (int r = 0; r < 4; ++r) acc[m][n][r] = 0.f;

  #pragma unroll 1
  for (int kk = 0; kk < 8; ++kk) {
    #pragma unroll
    for (int it = 0; it < 2; ++it) {
      int chunk = tid + it * 256;
      int c = chunk >> 2, q = chunk & 3;
      *reinterpret_cast<uint4*>(&sB[c][q * 8]) =
          *reinterpret_cast<const uint4*>(wu2T + c * 256 + kk * 32 + q * 8);
    }
    __syncthreads();
    bf16x8 aF[2], bF[4];
    #pragma unroll
    for (int m = 0; m < 2; ++m)
      aF[m] = __builtin_bit_cast(bf16x8, *reinterpret_cast<const uint4*>(
          t + (size_t)(n0 + wr * 32 + m * 16 + fr) * 256 + kk * 32 + fk));
    #pragma unroll
    for (int n = 0; n < 4; ++n)
      bF[n] = __builtin_bit_cast(bf16x8,
          *reinterpret_cast<const uint4*>(&sB[wc * 64 + n * 16 + fr][fk]));
    #pragma unroll
    for (int m = 0; m < 2; ++m)
      #pragma unroll
      for (int n = 0; n < 4; ++n)
        acc[m][n] = __builtin_amdgcn_mfma_f32_16x16x32_bf16(aF[m], bF[n], acc[m][n], 0, 0, 0);
    __syncthreads();
  }
  #pragma unroll
  for (int m = 0; m < 2; ++m) {
    #pragma unroll
    for (int r = 0; r < 4; ++r) {
      int gn = n0 + wr * 32 + m * 16 + orow + r;
      float inv = 1.f / fmaxf((float)cnt[gn], 1.f);
      #pragma unroll
      for (int n = 0; n < 4; ++n) {
        int col = wc * 64 + n * 16 + fr;
        float xi = x[(size_t)gn * HID + col] + sums[(size_t)gn * HID + col] * inv;
        xo[(size_t)gn * HID + col] = xi + acc[m][n][r] + bu2[col];
      }
    }
  }
}

// -------------------------------------------------------------- launch ----
extern "C" void kernel_launch(void* const* d_in, const int* in_sizes, int n_in,
                              void* d_out, int out_size, void* d_ws, size_t ws_size,
                              hipStream_t stream)
{
  (void)in_sizes; (void)n_in; (void)out_size; (void)ws_size;
  const float* x     = (const float*)d_in[0];
  const float* eattr = (const float*)d_in[1];
  const int*   edges = (const int*)d_in[2];
  const float* w1  = (const float*)d_in[3];
  const float* b1  = (const float*)d_in[4];
  const float* w2  = (const float*)d_in[5];
  const float* b2  = (const float*)d_in[6];
  const float* wu1 = (const float*)d_in[7];
  const float* bu1 = (const float*)d_in[8];
  const float* wu2 = (const float*)d_in[9];
  const float* bu2 = (const float*)d_in[10];

  float* xo  = (float*)d_out;
  float* msg = xo + (size_t)NN * HID;

  char* p = (char*)d_ws;                       // ~51 MB total
  u16* xb    = (u16*)p; p += (size_t)NN * HID * 2;
  u16* w1Ts  = (u16*)p; p += 384 * 128 * 2;    // contiguous with w2Ts (131072B)
  u16* w2Ts  = (u16*)p; p += 128 * 128 * 2;
  u16* wu1T  = (u16*)p; p += 256 * 128 * 2;
  u16* wu2T  = (u16*)p; p += 128 * 256 * 2;
  u16* tbuf  = (u16*)p; p += (size_t)NN * 256 * 2;
  float* sums = (float*)p; p += (size_t)NN * HID * 4;
  int* cnt    = (int*)p; p += (size_t)NN * 4;
  int* cursor = (int*)p; p += (size_t)NN * 4;
  int* eperm  = (int*)p; p += (size_t)NE * 4;
  int* sid    = (int*)p; p += (size_t)NE * 4;
  int* rid    = (int*)p; p += (size_t)NE * 4;

  const int* send = edges;
  const int* recv = edges + NE;

  hipMemsetAsync(cnt, 0, (size_t)NN * 4, stream);
  hipMemsetAsync(sums, 0, (size_t)NN * HID * 4, stream);
  prep_k<<<NN * HID / 4 / 256, 256, 0, stream>>>(x, w1, w2, wu1, wu2, recv,
                                                 xb, w1Ts, w2Ts, wu1T, wu2T, cnt);
  scan_k<<<1, 1024, 0, stream>>>(cnt, cursor);
  scatter_k<<<NE / 256, 256, 0, stream>>>(send, recv, cursor, eperm, sid, rid);
  edge_mlp<<<NE / 128, 512, 0, stream>>>(xb, eattr, eperm, sid, rid,
                                         w1Ts, b1, b2, msg, sums);
  mlp1_k<<<NN / 64, 256, 0, stream>>>(x, sums, cnt, wu1T, bu1, tbuf);
  mlp2_k<<<NN / 64, 256, 0, stream>>>(tbuf, wu2T, bu2, x, sums, cnt, xo);
}

// Round 16
// 323.451 us; speedup vs baseline: 1.1913x; 1.1913x over previous
//
#include <hip/hip_runtime.h>
#include <hip/hip_bf16.h>

#define NN 32768
#define NE 524288
#define HID 128

typedef unsigned short u16;
typedef unsigned int u32;
typedef __bf16 bf16x8 __attribute__((ext_vector_type(8)));
typedef float f32x4 __attribute__((ext_vector_type(4)));

__device__ __forceinline__ u16 f2bf(float f) {
  return __builtin_bit_cast(u16, (__bf16)f);   // RNE via v_cvt
}
__device__ __forceinline__ float bf2f(u16 h) {
  return __builtin_bit_cast(float, (u32)h << 16);
}
__device__ __forceinline__ float silu_f(float v) {
  return v * __builtin_amdgcn_rcpf(1.f + __expf(-v));
}
__device__ __forceinline__ bf16x8 cvt8(float4 a, float4 b) {
  bf16x8 r;
  r[0] = (__bf16)a.x; r[1] = (__bf16)a.y; r[2] = (__bf16)a.z; r[3] = (__bf16)a.w;
  r[4] = (__bf16)b.x; r[5] = (__bf16)b.y; r[6] = (__bf16)b.z; r[7] = (__bf16)b.w;
  return r;
}
__device__ __forceinline__ float4 f4fma(float4 x, float4 s, float inv) {
  return make_float4(x.x + s.x * inv, x.y + s.y * inv,
                     x.z + s.z * inv, x.w + s.w * inv);
}

// async global->LDS, 16B/lane; LDS dest = wave-uniform base + lane*16
__device__ __forceinline__ void gld16(const void* g, void* l) {
  __builtin_amdgcn_global_load_lds(
      (const __attribute__((address_space(1))) u32*)g,
      (__attribute__((address_space(3))) u32*)l, 16, 0, 0);
}

#define WV(N)  do { asm volatile("s_waitcnt vmcnt(" #N ")" ::: "memory"); \
                    __builtin_amdgcn_sched_barrier(0); } while (0)
#define WL()   do { asm volatile("s_waitcnt lgkmcnt(0)" ::: "memory"); \
                    __builtin_amdgcn_sched_barrier(0); } while (0)
__device__ __forceinline__ void bar() {
  __builtin_amdgcn_sched_barrier(0);
  __builtin_amdgcn_s_barrier();
  __builtin_amdgcn_sched_barrier(0);
}

// ---------------------------------------------------------------- prep ----
// VECTORIZED (float4/thread): x->bf16; w1/w2 -> col-major + 16B-chunk XOR
// pre-swizzle (w1Ts||w2Ts contiguous); wu1/wu2 plain col-major; fused
// recv-degree count (cnt pre-zeroed). Grid = NN*HID/4/256 = 4096 blocks;
// i covers [0, 1048576) > NE so the edge count is complete.
__global__ __launch_bounds__(256) void prep_k(
    const float* __restrict__ x, const float* __restrict__ w1,
    const float* __restrict__ w2, const float* __restrict__ wu1,
    const float* __restrict__ wu2, const int* __restrict__ recv,
    u16* __restrict__ xb, u16* __restrict__ w1Ts, u16* __restrict__ w2Ts,
    u16* __restrict__ wu1T, u16* __restrict__ wu2T, int* __restrict__ cnt)
{
  int i = blockIdx.x * 256 + threadIdx.x;     // 1048576 threads
  float4 xv = reinterpret_cast<const float4*>(x)[i];
  uint2 pv;
  pv.x = (u32)f2bf(xv.x) | ((u32)f2bf(xv.y) << 16);
  pv.y = (u32)f2bf(xv.z) | ((u32)f2bf(xv.w) << 16);
  reinterpret_cast<uint2*>(xb)[i] = pv;
  if (i < NE) atomicAdd(&cnt[recv[i]], 1);
  if (i < 3 * 128 * 128) {                    // w1Ts [s][c][q^(c&7)][j]
    int j = i & 7, qs = (i >> 3) & 15, c = (i >> 7) & 127, s = i >> 14;
    int k = s * 128 + ((qs ^ (c & 7)) << 3) + j;
    w1Ts[i] = f2bf(w1[k * 128 + c]);
  }
  if (i < 128 * 128) {                        // w2Ts [c][q^(c&7)][j]
    int j = i & 7, qs = (i >> 3) & 15, c = i >> 7;
    int k = ((qs ^ (c & 7)) << 3) + j;
    w2Ts[i] = f2bf(w2[k * 128 + c]);
  }
  if (i < 256 * 128) { int c = i >> 7, k = i & 127; wu1T[i] = f2bf(wu1[k * 256 + c]); }
  if (i < 128 * 256) { int c = i >> 8, k = i & 255; wu2T[i] = f2bf(wu2[k * 128 + c]); }
}

// exclusive scan of cnt[NN] -> cursor
__global__ __launch_bounds__(1024) void scan_k(const int* __restrict__ cnt,
                                               int* __restrict__ cursor)
{
  __shared__ int part[1024];
  const int tid = threadIdx.x;
  const int base = tid * 32;
  int v[32];
  int s = 0;
  #pragma unroll
  for (int j = 0; j < 32; ++j) { v[j] = cnt[base + j]; s += v[j]; }
  part[tid] = s;
  __syncthreads();
  #pragma unroll 1
  for (int d = 1; d < 1024; d <<= 1) {
    int t = (tid >= d) ? part[tid - d] : 0;
    __syncthreads();
    part[tid] += t;
    __syncthreads();
  }
  int ex = part[tid] - s;
  #pragma unroll
  for (int j = 0; j < 32; ++j) {
    cursor[base + j] = ex;
    ex += v[j];
  }
}

// CSR scatter; also pre-gathers send/recv into CSR order (sid/rid).
__global__ __launch_bounds__(256) void scatter_k(const int* __restrict__ send,
                                                 const int* __restrict__ recv,
                                                 int* __restrict__ cursor,
                                                 int* __restrict__ eperm,
                                                 int* __restrict__ sid,
                                                 int* __restrict__ rid)
{
  int e = blockIdx.x * 256 + threadIdx.x;
  int r = recv[e];
  int s = send[e];
  int pos = atomicAdd(&cursor[r], 1);
  eperm[pos] = e;
  sid[pos] = s;
  rid[pos] = r;
}

// ------------------------------------------------------------ edge MLP ----
// 3-blocks/CU phased kernel: 128 CSR edges/block, 8 waves, LDS 48.5KB
// (sA[128][128] 32KB + HALF B panel sB[64][128] 16KB + sNid). Wave tile
// 32x32 per half; acc[half][2][2]. Block-staged gld16. R16 delta vs R15:
// __launch_bounds__(512, 4) — the (512,6) hint forced a 40-VGPR alloc and
// +380MB spill traffic (R15 counters); with min=4 (cap 128 >> natural
// demand ~64-76) the allocator does not spill and LDS still admits
// 3 blocks/CU at runtime -> ~65% occupancy spill-free.
__global__ __launch_bounds__(512, 4) void edge_mlp(
    const u16* __restrict__ xb, const float* __restrict__ eattr,
    const int* __restrict__ eperm, const int* __restrict__ sid,
    const int* __restrict__ rid,
    const u16* __restrict__ wTs, const float* __restrict__ b1,
    const float* __restrict__ b2,
    float* __restrict__ msg_out, float* __restrict__ sums)
{
  __shared__ u16 sA[128 * 128];   // 32KB: A slices -> hidden -> msg-bf16
  __shared__ u16 sB[64 * 128];    // 16KB: one 64-col B half-panel
  __shared__ int sNid[128];

  const int tid  = threadIdx.x;
  const int lane = tid & 63;
  const int w    = tid >> 6;      // 0..7
  const int wr   = w >> 1;        // 0..3: 32-edge stripe
  const int wc   = w & 1;         // 0..1: col-32 within the current 64-col half
  const int fr   = lane & 15;
  const int fkq  = lane >> 4;
  const int orow = fkq * 4;
  const int lrow4 = lane >> 4;
  const int schk  = lane & 15;
  // bijective XCD-chunked tile mapping (gridDim = 4096, 4096 % 8 == 0)
  const int logical = ((int)blockIdx.x & 7) * ((int)gridDim.x >> 3)
                    + ((int)blockIdx.x >> 3);
  const int e0 = logical * 128;

  // ---- ids for this wave's 16 staging rows (single-hop: sid/rid) ----
  int eo[4], ns[4], nr[4], rl[4];
  #pragma unroll
  for (int i = 0; i < 4; ++i) {
    rl[i] = w * 16 + i * 4 + lrow4;
    eo[i] = eperm[e0 + rl[i]];
    ns[i] = sid[e0 + rl[i]];
    nr[i] = rid[e0 + rl[i]];
  }
  #pragma unroll
  for (int i = 0; i < 4; ++i)
    if (schk == 0) sNid[rl[i]] = nr[i];

  // bias values: col = h*64 + wc*32 + n*16 + fr
  float b1v[2][2], b2v[2][2];
  #pragma unroll
  for (int h = 0; h < 2; ++h)
    #pragma unroll
    for (int n = 0; n < 2; ++n) {
      int c = h * 64 + wc * 32 + n * 16 + fr;
      b1v[h][n] = b1[c];
      b2v[h][n] = b2[c];
    }

  f32x4 acc[2][2][2];             // [half][m][n]
  #pragma unroll
  for (int h = 0; h < 2; ++h)
    #pragma unroll
    for (int m = 0; m < 2; ++m)
      #pragma unroll
      for (int n = 0; n < 2; ++n)
        #pragma unroll
        for (int r = 0; r < 4; ++r) acc[h][m][n][r] = 0.f;

  // ---- staging helpers ----
  auto stageA = [&](const int (&node)[4]) {
    #pragma unroll
    for (int i = 0; i < 4; ++i)
      gld16(xb + ((size_t)node[i] << 7) + ((schk ^ (rl[i] & 7)) << 3),
            sA + ((w * 16 + i * 4) << 7));
  };
  // stage 16KB half-panel: 16 chunks x 512 u16 (1024B each; 64 lanes x 16B)
  auto stageB = [&](int panel, int h) {
    const u16* src = wTs + panel * 16384 + h * 8192;
    gld16(src + (w * 2 + 0) * 512 + lane * 8, sB + (w * 2 + 0) * 512);
    gld16(src + (w * 2 + 1) * 512 + lane * 8, sB + (w * 2 + 1) * 512);
  };

  // one 32x32 half-pass vs current sB
  auto chalf = [&](f32x4 (&a)[2][2]) {
    #pragma unroll
    for (int kk = 0; kk < 4; ++kk) {
      bf16x8 aF[2], bF[2];
      #pragma unroll
      for (int m = 0; m < 2; ++m) {
        int row = wr * 32 + m * 16 + fr;
        int ch = (kk * 4 + fkq) ^ (row & 7);
        aF[m] = __builtin_bit_cast(bf16x8,
            *reinterpret_cast<const uint4*>(sA + (row << 7) + (ch << 3)));
      }
      #pragma unroll
      for (int n = 0; n < 2; ++n) {
        int cl = wc * 32 + n * 16 + fr;
        int ch = (kk * 4 + fkq) ^ (cl & 7);
        bF[n] = __builtin_bit_cast(bf16x8,
            *reinterpret_cast<const uint4*>(sB + (cl << 7) + (ch << 3)));
      }
      __builtin_amdgcn_s_setprio(1);
      #pragma unroll
      for (int m = 0; m < 2; ++m)
        #pragma unroll
        for (int n = 0; n < 2; ++n)
          a[m][n] = __builtin_amdgcn_mfma_f32_16x16x32_bf16(aF[m], bF[n], a[m][n], 0, 0, 0);
      __builtin_amdgcn_s_setprio(0);
    }
  };

  // ---- slice 0: x[send] ----
  stageA(ns);
  stageB(0, 0);                    // W1a half0
  WV(0); bar();
  chalf(acc[0]); bar();            // s0 h0
  stageB(0, 1); WV(0); bar();
  chalf(acc[1]); bar();            // s0 h1

  // ---- slice 1: x[recv] ----
  stageA(nr);
  stageB(1, 0);
  WV(0); bar();
  chalf(acc[0]); bar();            // s1 h0
  stageB(1, 1); WV(0); bar();
  chalf(acc[1]); bar();            // s1 h1

  // ---- slice 2: eattr inline (load f32, cvt, swizzled ds_write) ----
  stageB(2, 0);
  #pragma unroll
  for (int i = 0; i < 4; ++i) {
    const float* ep = eattr + ((size_t)eo[i] << 7) + ((schk ^ (rl[i] & 7)) << 3);
    float4 v0 = *reinterpret_cast<const float4*>(ep);
    float4 v1 = *reinterpret_cast<const float4*>(ep + 4);
    *reinterpret_cast<uint4*>(sA + (rl[i] << 7) + (schk << 3)) =
        __builtin_bit_cast(uint4, cvt8(v0, v1));
  }
  WV(0); WL(); bar();
  chalf(acc[0]); bar();            // s2 h0
  stageB(2, 1); WV(0); bar();
  chalf(acc[1]); bar();            // s2 h1

  // hidden = silu(acc + b1) -> sA (swizzled b16) + stage W2 half0; reset acc
  stageB(3, 0);
  #pragma unroll
  for (int h = 0; h < 2; ++h)
    #pragma unroll
    for (int m = 0; m < 2; ++m)
      #pragma unroll
      for (int n = 0; n < 2; ++n) {
        int c = h * 64 + wc * 32 + n * 16 + fr;
        #pragma unroll
        for (int r = 0; r < 4; ++r) {
          int row = wr * 32 + m * 16 + orow + r;
          sA[(row << 7) + (((c >> 3) ^ (row & 7)) << 3) + (c & 7)] =
              f2bf(silu_f(acc[h][m][n][r] + b1v[h][n]));
          acc[h][m][n][r] = 0.f;
        }
      }
  WV(0); WL(); bar();
  chalf(acc[0]); bar();            // W2 h0
  stageB(3, 1); WV(0); bar();
  chalf(acc[1]);                   // W2 h1

  // epilogue edge ids (C/D rows)
  int eg[2][4];
  #pragma unroll
  for (int m = 0; m < 2; ++m)
    #pragma unroll
    for (int r = 0; r < 4; ++r)
      eg[m][r] = eperm[e0 + wr * 32 + m * 16 + orow + r];
  bar();                           // all slice-3 sA reads done

  // msg = silu(acc + b2) -> global f32 + bf16 -> sA for the reduce
  #pragma unroll
  for (int m = 0; m < 2; ++m)
    #pragma unroll
    for (int r = 0; r < 4; ++r) {
      int row = wr * 32 + m * 16 + orow + r;
      float* mp = msg_out + ((size_t)eg[m][r] << 7);
      #pragma unroll
      for (int h = 0; h < 2; ++h)
        #pragma unroll
        for (int n = 0; n < 2; ++n) {
          int c = h * 64 + wc * 32 + n * 16 + fr;
          float v = silu_f(acc[h][m][n][r] + b2v[h][n]);
          mp[c] = v;
          sA[(row << 7) + (((c >> 3) ^ (row & 7)) << 3) + (c & 7)] = f2bf(v);
        }
    }
  WL(); bar();

  // segmented column reduce: 4 groups x 32 rows, 128 cols
  {
    const int col = tid & 127, q = tid >> 7;
    float s = 0.f;
    int cur = sNid[q * 32];
    #pragma unroll 1
    for (int r = 0; r < 32; ++r) {
      int row = q * 32 + r;
      u16 hv = sA[(row << 7) + (((col >> 3) ^ (row & 7)) << 3) + (col & 7)];
      s += bf2f(hv);
      int nxt = (r < 31) ? sNid[row + 1] : -1;
      if (nxt != cur) {
        atomicAdd(sums + (size_t)cur * HID + col, s);
        s = 0.f;
        cur = nxt;
      }
    }
  }
}

// ----------------------------------------------------------- update MLP ----
// t = silu((x + sums/cnt) @ wu1 + bu1)  [NN,256] — xin fused into A-fragments
__global__ __launch_bounds__(256) void mlp1_k(
    const float* __restrict__ x, const float* __restrict__ sums,
    const int* __restrict__ cnt, const u16* __restrict__ wu1T,
    const float* __restrict__ bu1, u16* __restrict__ t)
{
  __shared__ u16 sB[256][40];
  const int tid = threadIdx.x, lane = tid & 63, wid = tid >> 6;
  const int wr = wid >> 1, wc = wid & 1;
  const int fr = lane & 15, fkq = lane >> 4, fk = fkq * 8, orow = fkq * 4;
  const int n0 = blockIdx.x * 64;

  float invm[2];
  #pragma unroll
  for (int m = 0; m < 2; ++m)
    invm[m] = __builtin_amdgcn_rcpf(fmaxf((float)cnt[n0 + wr * 32 + m * 16 + fr], 1.f));

  f32x4 acc[2][8];
  #pragma unroll
  for (int m = 0; m < 2; ++m)
    #pragma unroll
    for (int n = 0; n < 8; ++n)
      #pragma unroll
      for (int r = 0; r < 4; ++r) acc[m][n][r] = 0.f;

  #pragma unroll 1
  for (int kk = 0; kk < 4; ++kk) {
    #pragma unroll
    for (int it = 0; it < 4; ++it) {
      int chunk = tid + it * 256;
      int c = chunk >> 2, q = chunk & 3;
      *reinterpret_cast<uint4*>(&sB[c][q * 8]) =
          *reinterpret_cast<const uint4*>(wu1T + c * 128 + kk * 32 + q * 8);
    }
    __syncthreads();
    bf16x8 aF[2], bF[8];
    #pragma unroll
    for (int m = 0; m < 2; ++m) {
      size_t basei = (size_t)(n0 + wr * 32 + m * 16 + fr) * HID + kk * 32 + fk;
      float4 xv0 = *reinterpret_cast<const float4*>(x + basei);
      float4 xv1 = *reinterpret_cast<const float4*>(x + basei + 4);
      float4 sv0 = *reinterpret_cast<const float4*>(sums + basei);
      float4 sv1 = *reinterpret_cast<const float4*>(sums + basei + 4);
      aF[m] = cvt8(f4fma(xv0, sv0, invm[m]), f4fma(xv1, sv1, invm[m]));
    }
    #pragma unroll
    for (int n = 0; n < 8; ++n)
      bF[n] = __builtin_bit_cast(bf16x8,
          *reinterpret_cast<const uint4*>(&sB[wc * 128 + n * 16 + fr][fk]));
    #pragma unroll
    for (int m = 0; m < 2; ++m)
      #pragma unroll
      for (int n = 0; n < 8; ++n)
        acc[m][n] = __builtin_amdgcn_mfma_f32_16x16x32_bf16(aF[m], bF[n], acc[m][n], 0, 0, 0);
    __syncthreads();
  }
  #pragma unroll
  for (int n = 0; n < 8; ++n) {
    int col = wc * 128 + n * 16 + fr;
    float bb = bu1[col];
    #pragma unroll
    for (int m = 0; m < 2; ++m) {
      int row = n0 + wr * 32 + m * 16 + orow;
      #pragma unroll
      for (int r = 0; r < 4; ++r)
        t[(size_t)(row + r) * 256 + col] = f2bf(silu_f(acc[m][n][r] + bb));
    }
  }
}

// xo = (x + sums/cnt) + t @ wu2 + bu2   (residual recomputed in f32)
__global__ __launch_bounds__(256) void mlp2_k(
    const u16* __restrict__ t, const u16* __restrict__ wu2T,
    const float* __restrict__ bu2, const float* __restrict__ x,
    const float* __restrict__ sums, const int* __restrict__ cnt,
    float* __restrict__ xo)
{
  __shared__ u16 sB[128][40];
  const int tid = threadIdx.x, lane = tid & 63, wid = tid >> 6;
  const int wr = wid >> 1, wc = wid & 1;
  const int fr = lane & 15, fk = (lane >> 4) * 8, orow = (lane >> 4) * 4;
  const int n0 = blockIdx.x * 64;

  f32x4 acc[2][4];
  #pragma unroll
  for (int m = 0; m < 2; ++m)
    #pragma unroll
    for (int n = 0; n < 4; ++n)
      #pragma unroll
      for (int r = 0; r < 4; ++r) acc[m][n][r] = 0.f;

  #pragma unroll 1
  for (int kk = 0; kk < 8; ++kk) {
    #pragma unroll
    for (int it = 0; it < 2; ++it) {
      int chunk = tid + it * 256;
      int c = chunk >> 2, q = chunk & 3;
      *reinterpret_cast<uint4*>(&sB[c][q * 8]) =
          *reinterpret_cast<const uint4*>(wu2T + c * 256 + kk * 32 + q * 8);
    }
    __syncthreads();
    bf16x8 aF[2], bF[4];
    #pragma unroll
    for (int m = 0; m < 2; ++m)
      aF[m] = __builtin_bit_cast(bf16x8, *reinterpret_cast<const uint4*>(
          t + (size_t)(n0 + wr * 32 + m * 16 + fr) * 256 + kk * 32 + fk));
    #pragma unroll
    for (int n = 0; n < 4; ++n)
      bF[n] = __builtin_bit_cast(bf16x8,
          *reinterpret_cast<const uint4*>(&sB[wc * 64 + n * 16 + fr][fk]));
    #pragma unroll
    for (int m = 0; m < 2; ++m)
      #pragma unroll
      for (int n = 0; n < 4; ++n)
        acc[m][n] = __builtin_amdgcn_mfma_f32_16x16x32_bf16(aF[m], bF[n], acc[m][n], 0, 0, 0);
    __syncthreads();
  }
  #pragma unroll
  for (int m = 0; m < 2; ++m) {
    #pragma unroll
    for (int r = 0; r < 4; ++r) {
      int gn = n0 + wr * 32 + m * 16 + orow + r;
      float inv = 1.f / fmaxf((float)cnt[gn], 1.f);
      #pragma unroll
      for (int n = 0; n < 4; ++n) {
        int col = wc * 64 + n * 16 + fr;
        float xi = x[(size_t)gn * HID + col] + sums[(size_t)gn * HID + col] * inv;
        xo[(size_t)gn * HID + col] = xi + acc[m][n][r] + bu2[col];
      }
    }
  }
}

// -------------------------------------------------------------- launch ----
extern "C" void kernel_launch(void* const* d_in, const int* in_sizes, int n_in,
                              void* d_out, int out_size, void* d_ws, size_t ws_size,
                              hipStream_t stream)
{
  (void)in_sizes; (void)n_in; (void)out_size; (void)ws_size;
  const float* x     = (const float*)d_in[0];
  const float* eattr = (const float*)d_in[1];
  const int*   edges = (const int*)d_in[2];
  const float* w1  = (const float*)d_in[3];
  const float* b1  = (const float*)d_in[4];
  const float* w2  = (const float*)d_in[5];
  const float* b2  = (const float*)d_in[6];
  const float* wu1 = (const float*)d_in[7];
  const float* bu1 = (const float*)d_in[8];
  const float* wu2 = (const float*)d_in[9];
  const float* bu2 = (const float*)d_in[10];

  float* xo  = (float*)d_out;
  float* msg = xo + (size_t)NN * HID;

  char* p = (char*)d_ws;                       // ~51 MB total
  u16* xb    = (u16*)p; p += (size_t)NN * HID * 2;
  u16* w1Ts  = (u16*)p; p += 384 * 128 * 2;    // contiguous with w2Ts (131072B)
  u16* w2Ts  = (u16*)p; p += 128 * 128 * 2;
  u16* wu1T  = (u16*)p; p += 256 * 128 * 2;
  u16* wu2T  = (u16*)p; p += 128 * 256 * 2;
  u16* tbuf  = (u16*)p; p += (size_t)NN * 256 * 2;
  float* sums = (float*)p; p += (size_t)NN * HID * 4;
  int* cnt    = (int*)p; p += (size_t)NN * 4;
  int* cursor = (int*)p; p += (size_t)NN * 4;
  int* eperm  = (int*)p; p += (size_t)NE * 4;
  int* sid    = (int*)p; p += (size_t)NE * 4;
  int* rid    = (int*)p; p += (size_t)NE * 4;

  const int* send = edges;
  const int* recv = edges + NE;

  hipMemsetAsync(cnt, 0, (size_t)NN * 4, stream);
  hipMemsetAsync(sums, 0, (size_t)NN * HID * 4, stream);
  prep_k<<<NN * HID / 4 / 256, 256, 0, stream>>>(x, w1, w2, wu1, wu2, recv,
                                                 xb, w1Ts, w2Ts, wu1T, wu2T, cnt);
  scan_k<<<1, 1024, 0, stream>>>(cnt, cursor);
  scatter_k<<<NE / 256, 256, 0, stream>>>(send, recv, cursor, eperm, sid, rid);
  edge_mlp<<<NE / 128, 512, 0, stream>>>(xb, eattr, eperm, sid, rid,
                                         w1Ts, b1, b2, msg, sums);
  mlp1_k<<<NN / 64, 256, 0, stream>>>(x, sums, cnt, wu1T, bu1, tbuf);
  mlp2_k<<<NN / 64, 256, 0, stream>>>(tbuf, wu2T, bu2, x, sums, cnt, xo);
}

// Round 17
// 295.558 us; speedup vs baseline: 1.3037x; 1.0944x over previous
//
#include <hip/hip_runtime.h>
#include <hip/hip_bf16.h>

#define NN 32768
#define NE 524288
#define HID 128

typedef unsigned short u16;
typedef unsigned int u32;
typedef __bf16 bf16x8 __attribute__((ext_vector_type(8)));
typedef float f32x4 __attribute__((ext_vector_type(4)));

__device__ __forceinline__ u16 f2bf(float f) {
  return __builtin_bit_cast(u16, (__bf16)f);   // RNE via v_cvt
}
__device__ __forceinline__ float bf2f(u16 h) {
  return __builtin_bit_cast(float, (u32)h << 16);
}
__device__ __forceinline__ float silu_f(float v) {
  return v * __builtin_amdgcn_rcpf(1.f + __expf(-v));
}
__device__ __forceinline__ bf16x8 cvt8(float4 a, float4 b) {
  bf16x8 r;
  r[0] = (__bf16)a.x; r[1] = (__bf16)a.y; r[2] = (__bf16)a.z; r[3] = (__bf16)a.w;
  r[4] = (__bf16)b.x; r[5] = (__bf16)b.y; r[6] = (__bf16)b.z; r[7] = (__bf16)b.w;
  return r;
}
__device__ __forceinline__ float4 f4fma(float4 x, float4 s, float inv) {
  return make_float4(x.x + s.x * inv, x.y + s.y * inv,
                     x.z + s.z * inv, x.w + s.w * inv);
}

// async global->LDS, 16B/lane; LDS dest = wave-uniform base + lane*16
__device__ __forceinline__ void gld16(const void* g, void* l) {
  __builtin_amdgcn_global_load_lds(
      (const __attribute__((address_space(1))) u32*)g,
      (__attribute__((address_space(3))) u32*)l, 16, 0, 0);
}

#define WL()   do { asm volatile("s_waitcnt lgkmcnt(0)" ::: "memory"); \
                    __builtin_amdgcn_sched_barrier(0); } while (0)

// ---------------------------------------------------------------- prep ----
// VECTORIZED (float4/thread, proven R13/R15/R16): x->bf16; w1/w2 ->
// col-major + 16B-chunk XOR pre-swizzle (w1Ts||w2Ts contiguous 131072B);
// wu1/wu2 plain col-major; fused recv-degree count (cnt pre-zeroed).
// Grid = NN*HID/4/256 = 4096 blocks; i covers [0, 1048576) > NE.
__global__ __launch_bounds__(256) void prep_k(
    const float* __restrict__ x, const float* __restrict__ w1,
    const float* __restrict__ w2, const float* __restrict__ wu1,
    const float* __restrict__ wu2, const int* __restrict__ recv,
    u16* __restrict__ xb, u16* __restrict__ w1Ts, u16* __restrict__ w2Ts,
    u16* __restrict__ wu1T, u16* __restrict__ wu2T, int* __restrict__ cnt)
{
  int i = blockIdx.x * 256 + threadIdx.x;     // 1048576 threads
  float4 xv = reinterpret_cast<const float4*>(x)[i];
  uint2 pv;
  pv.x = (u32)f2bf(xv.x) | ((u32)f2bf(xv.y) << 16);
  pv.y = (u32)f2bf(xv.z) | ((u32)f2bf(xv.w) << 16);
  reinterpret_cast<uint2*>(xb)[i] = pv;
  if (i < NE) atomicAdd(&cnt[recv[i]], 1);
  if (i < 3 * 128 * 128) {                    // w1Ts [s][c][q^(c&7)][j]
    int j = i & 7, qs = (i >> 3) & 15, c = (i >> 7) & 127, s = i >> 14;
    int k = s * 128 + ((qs ^ (c & 7)) << 3) + j;
    w1Ts[i] = f2bf(w1[k * 128 + c]);
  }
  if (i < 128 * 128) {                        // w2Ts [c][q^(c&7)][j]
    int j = i & 7, qs = (i >> 3) & 15, c = i >> 7;
    int k = ((qs ^ (c & 7)) << 3) + j;
    w2Ts[i] = f2bf(w2[k * 128 + c]);
  }
  if (i < 256 * 128) { int c = i >> 7, k = i & 127; wu1T[i] = f2bf(wu1[k * 256 + c]); }
  if (i < 128 * 256) { int c = i >> 8, k = i & 255; wu2T[i] = f2bf(wu2[k * 128 + c]); }
}

// exclusive scan of cnt[NN] -> cursor
__global__ __launch_bounds__(1024) void scan_k(const int* __restrict__ cnt,
                                               int* __restrict__ cursor)
{
  __shared__ int part[1024];
  const int tid = threadIdx.x;
  const int base = tid * 32;
  int v[32];
  int s = 0;
  #pragma unroll
  for (int j = 0; j < 32; ++j) { v[j] = cnt[base + j]; s += v[j]; }
  part[tid] = s;
  __syncthreads();
  #pragma unroll 1
  for (int d = 1; d < 1024; d <<= 1) {
    int t = (tid >= d) ? part[tid - d] : 0;
    __syncthreads();
    part[tid] += t;
    __syncthreads();
  }
  int ex = part[tid] - s;
  #pragma unroll
  for (int j = 0; j < 32; ++j) {
    cursor[base + j] = ex;
    ex += v[j];
  }
}

// CSR scatter; also pre-gathers send/recv into CSR order (sid/rid).
__global__ __launch_bounds__(256) void scatter_k(const int* __restrict__ send,
                                                 const int* __restrict__ recv,
                                                 int* __restrict__ cursor,
                                                 int* __restrict__ eperm,
                                                 int* __restrict__ sid,
                                                 int* __restrict__ rid)
{
  int e = blockIdx.x * 256 + threadIdx.x;
  int r = recv[e];
  int s = send[e];
  int pos = atomicAdd(&cursor[r], 1);
  eperm[pos] = e;
  sid[pos] = s;
  rid[pos] = r;
}

// ------------------------------------------------------------ edge MLP ----
// R10 verbatim (measured best: 233us, VGPR 128, no spill). Persistent
// wave-autonomous kernel: 256 blocks x 8 waves; all 4 weight panels
// resident in LDS (128KB, ONE barrier); per-wave 2.5KB scratch; 8
// consecutive 32-edge CSR tiles per wave (XCD-chunked). A fragments
// per-lane direct from global (sid/rid pre-gathered ids), B from LDS,
// eattr direct + cvt_pk, layer-2 transpose via wave-private scratch
// (lgkmcnt only — DS in-order per wave), fused segmented reduce.
// Zero main-loop barriers. (512,2) is the only spill-free allocation for
// this ~180-VGPR-demand body (R11/R12/R15: any higher min-waves spills.)
__global__ __launch_bounds__(512, 2) void edge_mlp(
    const u16* __restrict__ xb, const float* __restrict__ eattr,
    const int* __restrict__ eperm, const int* __restrict__ sid,
    const int* __restrict__ rid,
    const u16* __restrict__ wTs, const float* __restrict__ b1,
    const float* __restrict__ b2,
    float* __restrict__ msg_out, float* __restrict__ sums)
{
  __shared__ u16 sW[65536];       // 128KB: panels 0..2 = W1abc, 3 = W2
  __shared__ u16 sT[8][1280];     // per-wave 32x40 transpose/reduce scratch

  const int tid  = threadIdx.x;
  const int lane = tid & 63;
  const int w    = tid >> 6;      // 0..7
  const int fr   = lane & 15;
  const int fkq  = lane >> 4;
  const int orow = fkq * 4;
  const int half = lane >> 5;     // reduce row-half
  const int cloc = lane & 31;     // reduce col within 32-chunk

  // ---- one-time weight load (131072B linear copy; panels pre-swizzled) ----
  #pragma unroll
  for (int i = 0; i < 16; ++i)
    gld16(wTs + (size_t)(i * 512 + tid) * 8, sW + (size_t)(i * 512 + w * 64) * 8);
  asm volatile("s_waitcnt vmcnt(0)" ::: "memory");
  __builtin_amdgcn_s_barrier();                 // the ONLY barrier

  float b1v[8], b2v[8];
  #pragma unroll
  for (int n = 0; n < 8; ++n) {
    b1v[n] = b1[n * 16 + fr];
    b2v[n] = b2[n * 16 + fr];
  }

  // tile domain: XCD chunk = blockIdx&7; 8 consecutive tiles per wave
  const int xcd = blockIdx.x & 7, jj = blockIdx.x >> 3;
  int base = (xcd * 2048 + (jj * 8 + w) * 8) * 32;

  // ids(0) — single-hop loads (sid/rid pre-gathered)
  int eoA = eperm[base + fr], eoB = eperm[base + 16 + fr];
  int nsA = sid[base + fr],   nsB = sid[base + 16 + fr];
  int nrA = rid[base + fr],   nrB = rid[base + 16 + fr];

  // A(0) direct-to-register (per-lane node-row gathers)
  bf16x8 a0[4][2], a1[4][2];
  #pragma unroll
  for (int kk = 0; kk < 4; ++kk) {
    a0[kk][0] = *reinterpret_cast<const bf16x8*>(xb + (size_t)nsA * 128 + kk * 32 + fkq * 8);
    a0[kk][1] = *reinterpret_cast<const bf16x8*>(xb + (size_t)nsB * 128 + kk * 32 + fkq * 8);
    a1[kk][0] = *reinterpret_cast<const bf16x8*>(xb + (size_t)nrA * 128 + kk * 32 + fkq * 8);
    a1[kk][1] = *reinterpret_cast<const bf16x8*>(xb + (size_t)nrB * 128 + kk * 32 + fkq * 8);
  }

  u16* tch = &sT[w][0];

  auto slice = [&](const bf16x8 (&A)[4][2], int P, f32x4 (&C)[2][8]) {
    #pragma unroll
    for (int kk = 0; kk < 4; ++kk) {
      bf16x8 bF[8];
      #pragma unroll
      for (int n = 0; n < 8; ++n) {
        int c = n * 16 + fr;
        int ch = (kk * 4 + fkq) ^ (c & 7);
        bF[n] = __builtin_bit_cast(bf16x8,
            *reinterpret_cast<const uint4*>(sW + P * 16384 + (c << 7) + (ch << 3)));
      }
      __builtin_amdgcn_s_setprio(1);
      #pragma unroll
      for (int m = 0; m < 2; ++m)
        #pragma unroll
        for (int n = 0; n < 8; ++n)
          C[m][n] = __builtin_amdgcn_mfma_f32_16x16x32_bf16(A[kk][m], bF[n], C[m][n], 0, 0, 0);
      __builtin_amdgcn_s_setprio(0);
    }
  };

  #pragma unroll 1
  for (int t = 0; t < 8; ++t) {
    // ---- issue EA(t) (rides under s0/s1) ----
    float4 ea[2][8];
    const float* epA = eattr + ((size_t)eoA << 7) + fkq * 8;
    const float* epB = eattr + ((size_t)eoB << 7) + fkq * 8;
    #pragma unroll
    for (int kk = 0; kk < 4; ++kk) {
      ea[0][2 * kk]     = *reinterpret_cast<const float4*>(epA + kk * 32);
      ea[0][2 * kk + 1] = *reinterpret_cast<const float4*>(epA + kk * 32 + 4);
      ea[1][2 * kk]     = *reinterpret_cast<const float4*>(epB + kk * 32);
      ea[1][2 * kk + 1] = *reinterpret_cast<const float4*>(epB + kk * 32 + 4);
    }
    // eg(t) for msg stores; ids(t+1); nid(t) for reduce
    int eg[2][4];
    #pragma unroll
    for (int m = 0; m < 2; ++m)
      #pragma unroll
      for (int r = 0; r < 4; ++r)
        eg[m][r] = eperm[base + m * 16 + orow + r];
    int nid[16];
    #pragma unroll
    for (int r = 0; r < 16; ++r) nid[r] = rid[base + half * 16 + r];
    int base1 = (t < 7) ? base + 32 : base;
    int eoA1 = eperm[base1 + fr], eoB1 = eperm[base1 + 16 + fr];
    int nsA1 = sid[base1 + fr],   nsB1 = sid[base1 + 16 + fr];
    int nrA1 = rid[base1 + fr],   nrB1 = rid[base1 + 16 + fr];
    __builtin_amdgcn_sched_barrier(0);

    // ---- layer 1 ----
    f32x4 acc[2][8];
    #pragma unroll
    for (int m = 0; m < 2; ++m)
      #pragma unroll
      for (int n = 0; n < 8; ++n)
        #pragma unroll
        for (int r = 0; r < 4; ++r) acc[m][n][r] = 0.f;

    slice(a0, 0, acc);                       // x[send] @ W1a
    slice(a1, 1, acc);                       // x[recv] @ W1b
    bf16x8 ae[4][2];
    #pragma unroll
    for (int kk = 0; kk < 4; ++kk) {
      ae[kk][0] = cvt8(ea[0][2 * kk], ea[0][2 * kk + 1]);
      ae[kk][1] = cvt8(ea[1][2 * kk], ea[1][2 * kk + 1]);
    }
    slice(ae, 2, acc);                       // eattr @ W1c

    // ---- layer 2: per-kk hidden transpose through per-wave scratch ----
    f32x4 acc2[2][8];
    #pragma unroll
    for (int m = 0; m < 2; ++m)
      #pragma unroll
      for (int n = 0; n < 8; ++n)
        #pragma unroll
        for (int r = 0; r < 4; ++r) acc2[m][n][r] = 0.f;

    #pragma unroll
    for (int kk = 0; kk < 4; ++kk) {
      #pragma unroll
      for (int m = 0; m < 2; ++m)
        #pragma unroll
        for (int nl = 0; nl < 2; ++nl) {
          int n = 2 * kk + nl;
          #pragma unroll
          for (int r = 0; r < 4; ++r)
            tch[(m * 16 + orow + r) * 40 + nl * 16 + fr] =
                f2bf(silu_f(acc[m][n][r] + b1v[n]));
        }
      WL();                                  // wave-private; DS in-order
      bf16x8 ah[2];
      ah[0] = __builtin_bit_cast(bf16x8,
          *reinterpret_cast<const uint4*>(tch + fr * 40 + fkq * 8));
      ah[1] = __builtin_bit_cast(bf16x8,
          *reinterpret_cast<const uint4*>(tch + (16 + fr) * 40 + fkq * 8));
      bf16x8 bF[8];
      #pragma unroll
      for (int n = 0; n < 8; ++n) {
        int c = n * 16 + fr;
        int ch = (kk * 4 + fkq) ^ (c & 7);
        bF[n] = __builtin_bit_cast(bf16x8,
            *reinterpret_cast<const uint4*>(sW + 3 * 16384 + (c << 7) + (ch << 3)));
      }
      __builtin_amdgcn_s_setprio(1);
      #pragma unroll
      for (int m = 0; m < 2; ++m)
        #pragma unroll
        for (int n = 0; n < 8; ++n)
          acc2[m][n] = __builtin_amdgcn_mfma_f32_16x16x32_bf16(ah[m], bF[n], acc2[m][n], 0, 0, 0);
      __builtin_amdgcn_s_setprio(0);
    }

    // ---- issue A(t+1) (rides under epilogue) ----
    #pragma unroll
    for (int kk = 0; kk < 4; ++kk) {
      a0[kk][0] = *reinterpret_cast<const bf16x8*>(xb + (size_t)nsA1 * 128 + kk * 32 + fkq * 8);
      a0[kk][1] = *reinterpret_cast<const bf16x8*>(xb + (size_t)nsB1 * 128 + kk * 32 + fkq * 8);
      a1[kk][0] = *reinterpret_cast<const bf16x8*>(xb + (size_t)nrA1 * 128 + kk * 32 + fkq * 8);
      a1[kk][1] = *reinterpret_cast<const bf16x8*>(xb + (size_t)nrB1 * 128 + kk * 32 + fkq * 8);
    }
    __builtin_amdgcn_sched_barrier(0);

    // ---- epilogue: msg stores + per-wave segmented reduce (4 col-chunks) ----
    #pragma unroll
    for (int cc = 0; cc < 4; ++cc) {
      #pragma unroll
      for (int m = 0; m < 2; ++m)
        #pragma unroll
        for (int nl = 0; nl < 2; ++nl) {
          int n = 2 * cc + nl;
          #pragma unroll
          for (int r = 0; r < 4; ++r) {
            float v = silu_f(acc2[m][n][r] + b2v[n]);
            msg_out[((size_t)eg[m][r] << 7) + n * 16 + fr] = v;
            tch[(m * 16 + orow + r) * 40 + nl * 16 + fr] = f2bf(v);
          }
        }
      WL();
      float s = 0.f;
      int cur = nid[0];
      #pragma unroll
      for (int r = 0; r < 16; ++r) {
        s += bf2f(tch[(half * 16 + r) * 40 + cloc]);
        int nxt = (r < 15) ? nid[r + 1] : -1;
        if (nxt != cur) {
          atomicAdd(sums + (size_t)cur * HID + cc * 32 + cloc, s);
          s = 0.f;
          cur = nxt;
        }
      }
      WL();                                  // reads done before next chunk's writes
    }

    // rotate to next tile
    base = base1;
    eoA = eoA1; eoB = eoB1;
  }
}

// ----------------------------------------------------------- update MLP ----
// t = silu((x + sums/cnt) @ wu1 + bu1)  [NN,256] — xin fused into A-fragments
__global__ __launch_bounds__(256) void mlp1_k(
    const float* __restrict__ x, const float* __restrict__ sums,
    const int* __restrict__ cnt, const u16* __restrict__ wu1T,
    const float* __restrict__ bu1, u16* __restrict__ t)
{
  __shared__ u16 sB[256][40];
  const int tid = threadIdx.x, lane = tid & 63, wid = tid >> 6;
  const int wr = wid >> 1, wc = wid & 1;
  const int fr = lane & 15, fkq = lane >> 4, fk = fkq * 8, orow = fkq * 4;
  const int n0 = blockIdx.x * 64;

  float invm[2];
  #pragma unroll
  for (int m = 0; m < 2; ++m)
    invm[m] = __builtin_amdgcn_rcpf(fmaxf((float)cnt[n0 + wr * 32 + m * 16 + fr], 1.f));

  f32x4 acc[2][8];
  #pragma unroll
  for (int m = 0; m < 2; ++m)
    #pragma unroll
    for (int n = 0; n < 8; ++n)
      #pragma unroll
      for (int r = 0; r < 4; ++r) acc[m][n][r] = 0.f;

  #pragma unroll 1
  for (int kk = 0; kk < 4; ++kk) {
    #pragma unroll
    for (int it = 0; it < 4; ++it) {
      int chunk = tid + it * 256;
      int c = chunk >> 2, q = chunk & 3;
      *reinterpret_cast<uint4*>(&sB[c][q * 8]) =
          *reinterpret_cast<const uint4*>(wu1T + c * 128 + kk * 32 + q * 8);
    }
    __syncthreads();
    bf16x8 aF[2], bF[8];
    #pragma unroll
    for (int m = 0; m < 2; ++m) {
      size_t basei = (size_t)(n0 + wr * 32 + m * 16 + fr) * HID + kk * 32 + fk;
      float4 xv0 = *reinterpret_cast<const float4*>(x + basei);
      float4 xv1 = *reinterpret_cast<const float4*>(x + basei + 4);
      float4 sv0 = *reinterpret_cast<const float4*>(sums + basei);
      float4 sv1 = *reinterpret_cast<const float4*>(sums + basei + 4);
      aF[m] = cvt8(f4fma(xv0, sv0, invm[m]), f4fma(xv1, sv1, invm[m]));
    }
    #pragma unroll
    for (int n = 0; n < 8; ++n)
      bF[n] = __builtin_bit_cast(bf16x8,
          *reinterpret_cast<const uint4*>(&sB[wc * 128 + n * 16 + fr][fk]));
    #pragma unroll
    for (int m = 0; m < 2; ++m)
      #pragma unroll
      for (int n = 0; n < 8; ++n)
        acc[m][n] = __builtin_amdgcn_mfma_f32_16x16x32_bf16(aF[m], bF[n], acc[m][n], 0, 0, 0);
    __syncthreads();
  }
  #pragma unroll
  for (int n = 0; n < 8; ++n) {
    int col = wc * 128 + n * 16 + fr;
    float bb = bu1[col];
    #pragma unroll
    for (int m = 0; m < 2; ++m) {
      int row = n0 + wr * 32 + m * 16 + orow;
      #pragma unroll
      for (int r = 0; r < 4; ++r)
        t[(size_t)(row + r) * 256 + col] = f2bf(silu_f(acc[m][n][r] + bb));
    }
  }
}

// xo = (x + sums/cnt) + t @ wu2 + bu2   (residual recomputed in f32)
__global__ __launch_bounds__(256) void mlp2_k(
    const u16* __restrict__ t, const u16* __restrict__ wu2T,
    const float* __restrict__ bu2, const float* __restrict__ x,
    const float* __restrict__ sums, const int* __restrict__ cnt,
    float* __restrict__ xo)
{
  __shared__ u16 sB[128][40];
  const int tid = threadIdx.x, lane = tid & 63, wid = tid >> 6;
  const int wr = wid >> 1, wc = wid & 1;
  const int fr = lane & 15, fk = (lane >> 4) * 8, orow = (lane >> 4) * 4;
  const int n0 = blockIdx.x * 64;

  f32x4 acc[2][4];
  #pragma unroll
  for (int m = 0; m < 2; ++m)
    #pragma unroll
    for (int n = 0; n < 4; ++n)
      #pragma unroll
      for (int r = 0; r < 4; ++r) acc[m][n][r] = 0.f;

  #pragma unroll 1
  for (int kk = 0; kk < 8; ++kk) {
    #pragma unroll
    for (int it = 0; it < 2; ++it) {
      int chunk = tid + it * 256;
      int c = chunk >> 2, q = chunk & 3;
      *reinterpret_cast<uint4*>(&sB[c][q * 8]) =
          *reinterpret_cast<const uint4*>(wu2T + c * 256 + kk * 32 + q * 8);
    }
    __syncthreads();
    bf16x8 aF[2], bF[4];
    #pragma unroll
    for (int m = 0; m < 2; ++m)
      aF[m] = __builtin_bit_cast(bf16x8, *reinterpret_cast<const uint4*>(
          t + (size_t)(n0 + wr * 32 + m * 16 + fr) * 256 + kk * 32 + fk));
    #pragma unroll
    for (int n = 0; n < 4; ++n)
      bF[n] = __builtin_bit_cast(bf16x8,
          *reinterpret_cast<const uint4*>(&sB[wc * 64 + n * 16 + fr][fk]));
    #pragma unroll
    for (int m = 0; m < 2; ++m)
      #pragma unroll
      for (int n = 0; n < 4; ++n)
        acc[m][n] = __builtin_amdgcn_mfma_f32_16x16x32_bf16(aF[m], bF[n], acc[m][n], 0, 0, 0);
    __syncthreads();
  }
  #pragma unroll
  for (int m = 0; m < 2; ++m) {
    #pragma unroll
    for (int r = 0; r < 4; ++r) {
      int gn = n0 + wr * 32 + m * 16 + orow + r;
      float inv = 1.f / fmaxf((float)cnt[gn], 1.f);
      #pragma unroll
      for (int n = 0; n < 4; ++n) {
        int col = wc * 64 + n * 16 + fr;
        float xi = x[(size_t)gn * HID + col] + sums[(size_t)gn * HID + col] * inv;
        xo[(size_t)gn * HID + col] = xi + acc[m][n][r] + bu2[col];
      }
    }
  }
}

// -------------------------------------------------------------- launch ----
extern "C" void kernel_launch(void* const* d_in, const int* in_sizes, int n_in,
                              void* d_out, int out_size, void* d_ws, size_t ws_size,
                              hipStream_t stream)
{
  (void)in_sizes; (void)n_in; (void)out_size; (void)ws_size;
  const float* x     = (const float*)d_in[0];
  const float* eattr = (const float*)d_in[1];
  const int*   edges = (const int*)d_in[2];
  const float* w1  = (const float*)d_in[3];
  const float* b1  = (const float*)d_in[4];
  const float* w2  = (const float*)d_in[5];
  const float* b2  = (const float*)d_in[6];
  const float* wu1 = (const float*)d_in[7];
  const float* bu1 = (const float*)d_in[8];
  const float* wu2 = (const float*)d_in[9];
  const float* bu2 = (const float*)d_in[10];

  float* xo  = (float*)d_out;
  float* msg = xo + (size_t)NN * HID;

  char* p = (char*)d_ws;                       // ~51 MB total
  u16* xb    = (u16*)p; p += (size_t)NN * HID * 2;
  u16* w1Ts  = (u16*)p; p += 384 * 128 * 2;    // contiguous with w2Ts (131072B)
  u16* w2Ts  = (u16*)p; p += 128 * 128 * 2;
  u16* wu1T  = (u16*)p; p += 256 * 128 * 2;
  u16* wu2T  = (u16*)p; p += 128 * 256 * 2;
  u16* tbuf  = (u16*)p; p += (size_t)NN * 256 * 2;
  float* sums = (float*)p; p += (size_t)NN * HID * 4;
  int* cnt    = (int*)p; p += (size_t)NN * 4;
  int* cursor = (int*)p; p += (size_t)NN * 4;
  int* eperm  = (int*)p; p += (size_t)NE * 4;
  int* sid    = (int*)p; p += (size_t)NE * 4;
  int* rid    = (int*)p; p += (size_t)NE * 4;

  const int* send = edges;
  const int* recv = edges + NE;

  hipMemsetAsync(cnt, 0, (size_t)NN * 4, stream);
  hipMemsetAsync(sums, 0, (size_t)NN * HID * 4, stream);
  prep_k<<<NN * HID / 4 / 256, 256, 0, stream>>>(x, w1, w2, wu1, wu2, recv,
                                                 xb, w1Ts, w2Ts, wu1T, wu2T, cnt);
  scan_k<<<1, 1024, 0, stream>>>(cnt, cursor);
  scatter_k<<<NE / 256, 256, 0, stream>>>(send, recv, cursor, eperm, sid, rid);
  edge_mlp<<<256, 512, 0, stream>>>(xb, eattr, eperm, sid, rid,
                                    w1Ts, b1, b2, msg, sums);
  mlp1_k<<<NN / 64, 256, 0, stream>>>(x, sums, cnt, wu1T, bu1, tbuf);
  mlp2_k<<<NN / 64, 256, 0, stream>>>(tbuf, wu2T, bu2, x, sums, cnt, xo);
}